// Round 4
// baseline (360.834 us; speedup 1.0000x reference)
//
#include <hip/hip_runtime.h>
#include <hip/hip_bf16.h>

// Problem constants
#define B_    8
#define N_    256
#define DN_   16
#define DE_   8
#define H_    64
#define Z_    64
#define L_    3
#define FC_   128
#define ROWS_ (B_ * N_)       // 2048
#define EDGES_ (B_ * N_ * N_) // 524288

using short8 = __attribute__((ext_vector_type(8))) short;
using f32x4t = __attribute__((ext_vector_type(4))) float;

__device__ __forceinline__ float fast_tanh(float x) {
    float e = __expf(2.0f * x);
    return 1.0f - 2.0f * __builtin_amdgcn_rcpf(e + 1.0f);
}

__device__ __forceinline__ unsigned short f2bf(float x) {
    unsigned int u = __float_as_uint(x);
    unsigned int r = (u + 0x7fffu + ((u >> 16) & 1u)) >> 16;   // RNE
    return (unsigned short)r;
}
__device__ __forceinline__ float bf2f(unsigned short u) {
    return __uint_as_float(((unsigned int)u) << 16);
}

// ---------------------------------------------------------------------------
// Kernel A: node embedding -> hcat segment 0
// ---------------------------------------------------------------------------
__global__ __launch_bounds__(128) void node_embed_kernel(
    const float* __restrict__ nf, const float* __restrict__ w1,
    const float* __restrict__ b1, const float* __restrict__ w2,
    const float* __restrict__ b2, float* __restrict__ hcat)
{
    int row = blockIdx.x;
    int t = threadIdx.x;
    __shared__ float x[DN_];
    __shared__ float hid[FC_];
    if (t < DN_) x[t] = nf[row * DN_ + t];
    __syncthreads();
    float a = b1[t];
#pragma unroll
    for (int c = 0; c < DN_; ++c) a += x[c] * w1[c * FC_ + t];
    hid[t] = fast_tanh(a);
    __syncthreads();
    if (t < H_) {
        float a2 = b2[t];
#pragma unroll
        for (int k = 0; k < FC_; ++k) a2 += hid[k] * w2[k * H_ + t];
        hcat[(size_t)row * 256 + t] = fast_tanh(a2);
    }
}

// ---------------------------------------------------------------------------
// Kernel B: edge MLP + channel sum.  Round-2 structure (empirically layout-
// correct) + double-bf16 split on BOTH operands for ~fp32 stage-2 precision.
// 128 edges / 128 threads / 2 waves per block; hi & lo h-tiles in LDS (2x32KB,
// same XOR-swizzled addressing as round 2); W2 hi/lo packed in-kernel per kk;
// 3-term MFMA (hh + lh + hl).
// ---------------------------------------------------------------------------
__global__ __launch_bounds__(128) void edge_mlp_mfma_kernel(
    const float* __restrict__ ef, const float* __restrict__ w1,
    const float* __restrict__ b1, const float* __restrict__ w2,
    const float* __restrict__ b2, float* __restrict__ ehs)
{
    __shared__ unsigned short hh[128 * FC_];   // 32 KB
    __shared__ unsigned short hl[128 * FC_];   // 32 KB

    int t = threadIdx.x;
    int lane = t & 63;
    int wid = t >> 6;
    size_t eb = (size_t)blockIdx.x * 128;
    int el = t;                     // edge_local 0..127
    size_t e = eb + el;

    // ---- stage 1: h = tanh(x@W1+b1); hi/lo bf16 into swizzled LDS ----
    const float4* ep = (const float4*)(ef + e * DE_);
    float4 x0 = ep[0], x1 = ep[1];
    float x[8] = {x0.x, x0.y, x0.z, x0.w, x1.x, x1.y, x1.z, x1.w};

    for (int g = 0; g < 16; ++g) {        // 16 groups of 8 channels
        short8 ph, pl;
#pragma unroll
        for (int kb = 0; kb < 8; ++kb) {
            int k = g * 8 + kb;
            float a = b1[k];
#pragma unroll
            for (int c = 0; c < 8; ++c) a += x[c] * w1[c * FC_ + k];
            float h = fast_tanh(a);
            unsigned short hi = f2bf(h);
            unsigned short lo = f2bf(h - bf2f(hi));
            ph[kb] = (short)hi;
            pl[kb] = (short)lo;
        }
        int slot = g ^ (el & 7);
        *(short8*)&hh[el * FC_ + slot * 8] = ph;
        *(short8*)&hl[el * FC_ + slot * 8] = pl;
    }
    __syncthreads();

    // ---- stage 2: MFMA  acc[64 edges x 64 out] per wave, K=128, 3 terms ----
    int krow = (lane >> 4) * 8;
    int col0 = lane & 15;
    float b2v[4];
#pragma unroll
    for (int ot = 0; ot < 4; ++ot) b2v[ot] = b2[ot * 16 + col0];
    f32x4t acc[4][4];
#pragma unroll
    for (int et = 0; et < 4; ++et)
#pragma unroll
        for (int ot = 0; ot < 4; ++ot)
            acc[et][ot] = (f32x4t){b2v[et * 0 + ot] * 0.f + b2v[ot], b2v[ot], b2v[ot], b2v[ot]};

#pragma unroll
    for (int kk = 0; kk < 4; ++kk) {
        // W2 fragments hi/lo (strided scalar loads, L1-resident; round-2 pattern)
        short8 wh[4], wl[4];
#pragma unroll
        for (int ot = 0; ot < 4; ++ot) {
#pragma unroll
            for (int b = 0; b < 8; ++b) {
                float v = w2[(kk * 32 + krow + b) * H_ + ot * 16 + col0];
                unsigned short hi = f2bf(v);
                unsigned short lo = f2bf(v - bf2f(hi));
                wh[ot][b] = (short)hi;
                wl[ot][b] = (short)lo;
            }
        }
        // A fragments hi/lo from LDS (round-2 addressing verbatim)
        short8 afh[4], afl[4];
#pragma unroll
        for (int et = 0; et < 4; ++et) {
            int er = wid * 64 + et * 16 + (lane & 15);
            int slot = (kk * 4 + (lane >> 4)) ^ (er & 7);
            afh[et] = *(const short8*)&hh[er * FC_ + slot * 8];
            afl[et] = *(const short8*)&hl[er * FC_ + slot * 8];
        }
#pragma unroll
        for (int et = 0; et < 4; ++et)
#pragma unroll
            for (int ot = 0; ot < 4; ++ot) {
                acc[et][ot] = __builtin_amdgcn_mfma_f32_16x16x32_bf16(
                    afh[et], wh[ot], acc[et][ot], 0, 0, 0);
                acc[et][ot] = __builtin_amdgcn_mfma_f32_16x16x32_bf16(
                    afl[et], wh[ot], acc[et][ot], 0, 0, 0);
                acc[et][ot] = __builtin_amdgcn_mfma_f32_16x16x32_bf16(
                    afh[et], wl[ot], acc[et][ot], 0, 0, 0);
            }
    }

    // ---- final: ehs[edge] = sum_o tanh(acc); reduce over 16 output-lanes ----
#pragma unroll
    for (int et = 0; et < 4; ++et)
#pragma unroll
        for (int r = 0; r < 4; ++r) {
            float v = fast_tanh(acc[et][0][r]) + fast_tanh(acc[et][1][r])
                    + fast_tanh(acc[et][2][r]) + fast_tanh(acc[et][3][r]);
            v += __shfl_xor(v, 1);
            v += __shfl_xor(v, 2);
            v += __shfl_xor(v, 4);
            v += __shfl_xor(v, 8);
            if ((lane & 15) == 0)
                ehs[eb + wid * 64 + et * 16 + (lane >> 4) * 4 + r] = v;
        }
}

// ---------------------------------------------------------------------------
// Kernel C1 per layer: h = tanh( (adj @ hidden) @ gcn_w )
// ---------------------------------------------------------------------------
__global__ __launch_bounds__(256) void gcn_kernel(
    const float* __restrict__ adj, const float* __restrict__ hcat,
    const float* __restrict__ gw, float* __restrict__ h, int seg)
{
    int wid = threadIdx.x >> 6;
    int lane = threadIdx.x & 63;
    int row = __builtin_amdgcn_readfirstlane(blockIdx.x * 4 + wid);
    int b = row >> 8;
    const float* arow = adj + (size_t)row * N_;
    const float* hb = hcat + (size_t)b * N_ * 256 + seg * H_;
    float g = 0.f;
    for (int j = 0; j < N_; ++j) g += arow[j] * hb[j * 256 + lane];
    __shared__ float gs[4][H_];
    gs[wid][lane] = g;
    __syncthreads();
    float a = 0.f;
#pragma unroll
    for (int k = 0; k < H_; ++k) a += gs[wid][k] * gw[k * H_ + lane];
    h[(size_t)row * H_ + lane] = fast_tanh(a);
}

// ---------------------------------------------------------------------------
// Kernel C2 per layer: comb + combine linear -> next hcat segment
// ---------------------------------------------------------------------------
__global__ __launch_bounds__(256) void comb_kernel(
    const float* __restrict__ ehs, const float* __restrict__ h,
    const float* __restrict__ cw, const float* __restrict__ cb,
    float* __restrict__ hcat, int seg)
{
    int wid = threadIdx.x >> 6;
    int lane = threadIdx.x & 63;
    int row = __builtin_amdgcn_readfirstlane(blockIdx.x * 4 + wid);
    int b = row >> 8;
    const float* er = ehs + (size_t)row * N_;
    const float* hb = h + (size_t)b * N_ * H_;
    float c = 0.f;
    for (int j = 0; j < N_; ++j) c += er[j] * hb[j * H_ + lane];
    c = fast_tanh(c);
    __shared__ float ch[4][H_], hi[4][H_];
    ch[wid][lane] = c;
    hi[wid][lane] = h[(size_t)row * H_ + lane];
    __syncthreads();
    float a = cb[lane];
#pragma unroll
    for (int k = 0; k < H_; ++k) a += hi[wid][k] * cw[k * H_ + lane];
#pragma unroll
    for (int k = 0; k < H_; ++k) a += ch[wid][k] * cw[(H_ + k) * H_ + lane];
    hcat[(size_t)row * 256 + (seg + 1) * H_ + lane] = fast_tanh(a);
}

// ---------------------------------------------------------------------------
// Kernel D: mean / logvar heads + latent
// ---------------------------------------------------------------------------
__global__ __launch_bounds__(128) void head_kernel(
    const float* __restrict__ hcat, const float* __restrict__ noise,
    const float* __restrict__ m1w, const float* __restrict__ m1b,
    const float* __restrict__ m2w, const float* __restrict__ m2b,
    const float* __restrict__ v1w, const float* __restrict__ v1b,
    const float* __restrict__ v2w, const float* __restrict__ v2b,
    float* __restrict__ out)
{
    const int G = 8;
    int row0 = blockIdx.x * G;
    int t = threadIdx.x;
    __shared__ float rbT[256][G];
    __shared__ float hid[G][FC_];
    __shared__ float ms[G][H_];
    for (int idx = t; idx < 256 * G; idx += 128) {
        int k = idx >> 3, g = idx & 7;
        rbT[k][g] = hcat[(size_t)(row0 + g) * 256 + k];
    }
    __syncthreads();

    float acc[G];
#pragma unroll
    for (int g = 0; g < G; ++g) acc[g] = m1b[t];
    for (int k = 0; k < 256; ++k) {
        float w = m1w[k * FC_ + t];
        const float4* rp = (const float4*)&rbT[k][0];
        float4 r0 = rp[0], r1 = rp[1];
        acc[0] += r0.x * w; acc[1] += r0.y * w; acc[2] += r0.z * w; acc[3] += r0.w * w;
        acc[4] += r1.x * w; acc[5] += r1.y * w; acc[6] += r1.z * w; acc[7] += r1.w * w;
    }
#pragma unroll
    for (int g = 0; g < G; ++g) hid[g][t] = fast_tanh(acc[g]);
    __syncthreads();
    if (t < H_) {
#pragma unroll
        for (int g = 0; g < G; ++g) {
            float m = m2b[t];
            for (int k = 0; k < FC_; ++k) m += hid[g][k] * m2w[k * H_ + t];
            ms[g][t] = m;
            out[(size_t)ROWS_ * Z_ + (size_t)(row0 + g) * H_ + t] = m;
        }
    }
    __syncthreads();

#pragma unroll
    for (int g = 0; g < G; ++g) acc[g] = v1b[t];
    for (int k = 0; k < 256; ++k) {
        float w = v1w[k * FC_ + t];
        const float4* rp = (const float4*)&rbT[k][0];
        float4 r0 = rp[0], r1 = rp[1];
        acc[0] += r0.x * w; acc[1] += r0.y * w; acc[2] += r0.z * w; acc[3] += r0.w * w;
        acc[4] += r1.x * w; acc[5] += r1.y * w; acc[6] += r1.z * w; acc[7] += r1.w * w;
    }
#pragma unroll
    for (int g = 0; g < G; ++g) hid[g][t] = fast_tanh(acc[g]);
    __syncthreads();
    if (t < H_) {
#pragma unroll
        for (int g = 0; g < G; ++g) {
            float lv = v2b[t];
            for (int k = 0; k < FC_; ++k) lv += hid[g][k] * v2w[k * H_ + t];
            out[(size_t)2 * ROWS_ * Z_ + (size_t)(row0 + g) * H_ + t] = lv;
            float lat = noise[(size_t)(row0 + g) * H_ + t] * __expf(0.5f * lv) + ms[g][t];
            out[(size_t)(row0 + g) * H_ + t] = lat;
        }
    }
}

extern "C" void kernel_launch(void* const* d_in, const int* in_sizes, int n_in,
                              void* d_out, int out_size, void* d_ws, size_t ws_size,
                              hipStream_t stream)
{
    const float* adj   = (const float*)d_in[0];
    const float* nf    = (const float*)d_in[1];
    const float* ef    = (const float*)d_in[2];
    const float* noise = (const float*)d_in[3];
    const float* nw1 = (const float*)d_in[4];  const float* nb1 = (const float*)d_in[5];
    const float* nw2 = (const float*)d_in[6];  const float* nb2 = (const float*)d_in[7];
    const float* ew1 = (const float*)d_in[8];  const float* eb1 = (const float*)d_in[9];
    const float* ew2 = (const float*)d_in[10]; const float* eb2 = (const float*)d_in[11];
    const float* gw  = (const float*)d_in[12];
    const float* cw  = (const float*)d_in[13]; const float* cb = (const float*)d_in[14];
    const float* m1w = (const float*)d_in[15]; const float* m1b = (const float*)d_in[16];
    const float* m2w = (const float*)d_in[17]; const float* m2b = (const float*)d_in[18];
    const float* v1w = (const float*)d_in[19]; const float* v1b = (const float*)d_in[20];
    const float* v2w = (const float*)d_in[21]; const float* v2b = (const float*)d_in[22];

    float* out  = (float*)d_out;
    float* ws   = (float*)d_ws;
    float* hcat = ws;                 // 524288 floats
    float* ehs  = ws + 524288;        // 524288 floats
    float* h    = ws + 1048576;       // 131072 floats

    hipLaunchKernelGGL(node_embed_kernel, dim3(ROWS_), dim3(128), 0, stream,
                       nf, nw1, nb1, nw2, nb2, hcat);
    hipLaunchKernelGGL(edge_mlp_mfma_kernel, dim3(EDGES_ / 128), dim3(128), 0, stream,
                       ef, ew1, eb1, ew2, eb2, ehs);
    for (int l = 0; l < L_; ++l) {
        hipLaunchKernelGGL(gcn_kernel, dim3(ROWS_ / 4), dim3(256), 0, stream,
                           adj, hcat, gw + l * H_ * H_, h, l);
        hipLaunchKernelGGL(comb_kernel, dim3(ROWS_ / 4), dim3(256), 0, stream,
                           ehs, h, cw + l * 2 * H_ * H_, cb + l * H_, hcat, l);
    }
    hipLaunchKernelGGL(head_kernel, dim3(ROWS_ / 8), dim3(128), 0, stream,
                       hcat, noise, m1w, m1b, m2w, m2b, v1w, v1b, v2w, v2b, out);
}